// Round 16
// baseline (171.049 us; speedup 1.0000x reference)
//
#include <hip/hip_runtime.h>
#include <hip/hip_fp16.h>
#include <hip/hip_bf16.h>

#define D 128
#define NRR 16      // ranges (2 per XCD under blockIdx%8 round-robin)
#define NCH 32      // chunks per range
#define CVT_BLOCKS 512
#define RE_SL 1600   // >= ceil(E/16)
#define RV_SL 6272   // >= ceil(N/16)

typedef __attribute__((ext_vector_type(8))) short bf16x8;
typedef __attribute__((ext_vector_type(4))) float f32x4;

__device__ __forceinline__ __half2 u2h(unsigned u) { return __builtin_bit_cast(__half2, u); }
__device__ __forceinline__ unsigned pack_h2(float a, float b) {
  __half2 h = __float22half2_rn(make_float2(a, b));
  return __builtin_bit_cast(unsigned, h);
}
__device__ __forceinline__ ushort f2bf(float x) {
  __hip_bfloat16 b = __float2bfloat16(x);
  return __builtin_bit_cast(ushort, b);
}

// ------- count: per-(range,chunk) LDS histograms -> dense tables; + cvt ----
__global__ __launch_bounds__(512) void count_tab(
    const int* __restrict__ edges, const int* __restrict__ vertex,
    int* __restrict__ T_E, int* __restrict__ T_V, int E, int N, int M,
    const float* __restrict__ X, uint2* __restrict__ Xh,
    const float* __restrict__ X0, uint2* X0h, int do_x0, int xn4) {
  __shared__ int he[RE_SL];
  __shared__ int hv[RV_SL];
  int b = blockIdx.x;
  if (b >= NRR * NCH) {
    const f32x4* X4 = (const f32x4*)X;
    const f32x4* X04 = (const f32x4*)X0;
    int stride = (gridDim.x - NRR * NCH) * 512;
    int lim = do_x0 ? (2 * xn4) : xn4;
    for (int i = (b - NRR * NCH) * 512 + threadIdx.x; i < lim; i += stride) {
      int j = (i < xn4) ? i : (i - xn4);
      f32x4 v = (i < xn4) ? X4[j] : X04[j];
      uint2 o = make_uint2(pack_h2(v[0], v[1]), pack_h2(v[2], v[3]));
      if (i < xn4) Xh[j] = o; else X0h[j] = o;
    }
    return;
  }
  int r = b & (NRR - 1), c = b >> 4;
  int RE = (E + NRR - 1) / NRR, RV = (N + NRR - 1) / NRR;
  int eLo = r * RE, eHi = min(eLo + RE, E);
  int vLo = r * RV, vHi = min(vLo + RV, N);
  int eLen = eHi - eLo, vLen = vHi - vLo;
  for (int i = threadIdx.x; i < eLen; i += 512) he[i] = 0;
  for (int i = threadIdx.x; i < vLen; i += 512) hv[i] = 0;
  __syncthreads();
  const int4* E4 = (const int4*)edges;
  const int4* V4 = (const int4*)vertex;
  int m4 = M >> 2;
  int per = (m4 + NCH - 1) / NCH;
  int i0 = c * per, i1 = min(i0 + per, m4);

#define PROC_CNT(ek, vk)                                               \
  {                                                                    \
    if ((ek).x >= eLo && (ek).x < eHi) atomicAdd(&he[(ek).x - eLo], 1);\
    if ((ek).y >= eLo && (ek).y < eHi) atomicAdd(&he[(ek).y - eLo], 1);\
    if ((ek).z >= eLo && (ek).z < eHi) atomicAdd(&he[(ek).z - eLo], 1);\
    if ((ek).w >= eLo && (ek).w < eHi) atomicAdd(&he[(ek).w - eLo], 1);\
    if ((vk).x >= vLo && (vk).x < vHi) atomicAdd(&hv[(vk).x - vLo], 1);\
    if ((vk).y >= vLo && (vk).y < vHi) atomicAdd(&hv[(vk).y - vLo], 1);\
    if ((vk).z >= vLo && (vk).z < vHi) atomicAdd(&hv[(vk).z - vLo], 1);\
    if ((vk).w >= vLo && (vk).w < vHi) atomicAdd(&hv[(vk).w - vLo], 1);\
  }

  int i = i0 + threadIdx.x;
  for (; i + 1536 < i1; i += 2048) {
    int4 e0 = E4[i], e1 = E4[i + 512], e2 = E4[i + 1024], e3 = E4[i + 1536];
    int4 v0 = V4[i], v1 = V4[i + 512], v2 = V4[i + 1024], v3 = V4[i + 1536];
    PROC_CNT(e0, v0); PROC_CNT(e1, v1); PROC_CNT(e2, v2); PROC_CNT(e3, v3);
  }
  for (; i < i1; i += 512) {
    int4 ek = E4[i];
    int4 vk = V4[i];
    PROC_CNT(ek, vk);
  }
  if (c == NCH - 1) {
    for (int m = (m4 << 2) + threadIdx.x; m < M; m += 512) {
      int e = edges[m], v = vertex[m];
      if (e >= eLo && e < eHi) atomicAdd(&he[e - eLo], 1);
      if (v >= vLo && v < vHi) atomicAdd(&hv[v - vLo], 1);
    }
  }
  __syncthreads();
  for (int i2 = threadIdx.x; i2 < eLen; i2 += 512) T_E[(size_t)c * E + eLo + i2] = he[i2];
  for (int i2 = threadIdx.x; i2 < vLen; i2 += 512) T_V[(size_t)c * N + vLo + i2] = hv[i2];
}

// ---------------- block exclusive scan helper ------------------------------
__device__ __forceinline__ int block_exscan(int x, int tid, int* wsum) {
  int lane = tid & 63, w = tid >> 6;
  int v = x;
  #pragma unroll
  for (int off = 1; off < 64; off <<= 1) {
    int t = __shfl_up(v, off);
    if (lane >= off) v += t;
  }
  if (lane == 63) wsum[w] = v;
  __syncthreads();
  if (w == 0 && lane < 16) {
    int s = wsum[lane];
    #pragma unroll
    for (int off = 1; off < 16; off <<= 1) {
      int t = __shfl_up(s, off);
      if (lane >= off) s += t;
    }
    wsum[lane] = s;
  }
  __syncthreads();
  int woff = (w == 0) ? 0 : wsum[w - 1];
  return woff + v - x;
}

// ------- fused: per-id chunk prefix (T in place) + C + local scan ----------
__global__ __launch_bounds__(1024) void scan_fused(
    int* __restrict__ T_E, int* __restrict__ C_E, int* __restrict__ A_E, int E,
    int* __restrict__ T_V, int* __restrict__ C_V, int* __restrict__ A_V, int N,
    int* __restrict__ sums, int BE) {
  __shared__ int wsum[16];
  int b = blockIdx.x;
  bool isE = b < BE;
  int* T = isE ? T_E : T_V;
  int* C = isE ? C_E : C_V;
  int* A = isE ? A_E : A_V;
  int len = isE ? E : N;
  int base = (isE ? b : (b - BE)) << 10;
  int id = base + threadIdx.x;
  int run = 0;
  if (id < len) {
    #pragma unroll
    for (int c = 0; c < NCH; ++c) {
      int t = T[(size_t)c * len + id];
      T[(size_t)c * len + id] = run;
      run += t;
    }
    C[id] = run;
  }
  int ex = block_exscan(run, threadIdx.x, wsum);
  if (id < len) A[id] = ex;
  if (threadIdx.x == 0) sums[b] = wsum[15];
}

// ------- add block offsets (redundant local scan of sums) + wprep ----------
__global__ __launch_bounds__(1024) void scan_add2(
    int* __restrict__ A_E, int E, int* __restrict__ A_V, int N,
    const int* __restrict__ sums, int BE, int BV,
    const float* __restrict__ W, const float* __restrict__ beta_p,
    ushort* __restrict__ Wbf) {
  int nb = BE + BV;
  if ((int)blockIdx.x >= nb) {  // wprep blocks
    int idx = (blockIdx.x - nb) * 1024 + threadIdx.x;
    if (idx < D * D) {
      int j = idx >> 7, k = idx & 127;
      float beta = *beta_p;
      float v = beta * W[idx] + ((j == k) ? (1.f - beta) : 0.f);
      Wbf[idx] = f2bf(v);
    }
    return;
  }
  __shared__ int wsum[16];
  __shared__ int pb, pbe;
  int x = ((int)threadIdx.x < nb) ? sums[threadIdx.x] : 0;
  int ex = block_exscan(x, threadIdx.x, wsum);
  if (threadIdx.x == blockIdx.x) pb = ex;
  if ((int)threadIdx.x == BE) pbe = ex;
  __syncthreads();
  bool isE = (int)blockIdx.x < BE;
  int off = isE ? pb : (pb - pbe);
  int* A = isE ? A_E : A_V;
  int len = isE ? E : N;
  int base = (isE ? blockIdx.x : (blockIdx.x - BE)) << 10;
  int i = base + threadIdx.x;
  if (i < len) A[i] += off;
}

// ------- scatter: deterministic slots, LDS-only ranking; x2 unroll ---------
__global__ __launch_bounds__(512) void scatter_tab(
    const int* __restrict__ edges, const int* __restrict__ vertex,
    const int* __restrict__ A_E, const int* __restrict__ A_V,
    const int* __restrict__ T_E, const int* __restrict__ T_V,
    int* __restrict__ colE, int* __restrict__ colV, int E, int N, int M) {
  __shared__ int offE[RE_SL];
  __shared__ int curE[RE_SL];
  __shared__ int offV[RV_SL];
  __shared__ int curV[RV_SL];
  int b = blockIdx.x;
  int r = b & (NRR - 1), c = b >> 4;
  int RE = (E + NRR - 1) / NRR, RV = (N + NRR - 1) / NRR;
  int eLo = r * RE, eHi = min(eLo + RE, E);
  int vLo = r * RV, vHi = min(vLo + RV, N);
  int eLen = eHi - eLo, vLen = vHi - vLo;
  for (int i = threadIdx.x; i < eLen; i += 512) {
    offE[i] = A_E[eLo + i] + T_E[(size_t)c * E + eLo + i];
    curE[i] = 0;
  }
  for (int i = threadIdx.x; i < vLen; i += 512) {
    offV[i] = A_V[vLo + i] + T_V[(size_t)c * N + vLo + i];
    curV[i] = 0;
  }
  __syncthreads();
  const int4* E4 = (const int4*)edges;
  const int4* V4 = (const int4*)vertex;
  int m4 = M >> 2;
  int per = (m4 + NCH - 1) / NCH;
  int i0 = c * per, i1 = min(i0 + per, m4);

#define PROC_SCAT(ek, vk)                                                   \
  {                                                                         \
    int es_[4] = {(ek).x, (ek).y, (ek).z, (ek).w};                          \
    int vs_[4] = {(vk).x, (vk).y, (vk).z, (vk).w};                          \
    _Pragma("unroll")                                                       \
    for (int t = 0; t < 4; ++t) {                                           \
      if (es_[t] >= eLo && es_[t] < eHi) {                                  \
        int p2 = atomicAdd(&curE[es_[t] - eLo], 1);                         \
        colE[offE[es_[t] - eLo] + p2] = vs_[t];                             \
      }                                                                     \
      if (vs_[t] >= vLo && vs_[t] < vHi) {                                  \
        int p2 = atomicAdd(&curV[vs_[t] - vLo], 1);                         \
        colV[offV[vs_[t] - vLo] + p2] = es_[t];                             \
      }                                                                     \
    }                                                                       \
  }

  int i = i0 + threadIdx.x;
  for (; i + 512 < i1; i += 1024) {
    int4 ea = E4[i], eb = E4[i + 512];
    int4 va = V4[i], vb = V4[i + 512];
    PROC_SCAT(ea, va);
    PROC_SCAT(eb, vb);
  }
  for (; i < i1; i += 512) {
    int4 ek = E4[i];
    int4 vk = V4[i];
    PROC_SCAT(ek, vk);
  }
  if (c == NCH - 1) {
    for (int m = (m4 << 2) + threadIdx.x; m < M; m += 512) {
      int e = edges[m], v = vertex[m];
      if (e >= eLo && e < eHi) {
        int p = atomicAdd(&curE[e - eLo], 1);
        colE[offE[e - eLo] + p] = v;
      }
      if (v >= vLo && v < vHi) {
        int p = atomicAdd(&curV[v - vLo], 1);
        colV[offV[v - vLo] + p] = e;
      }
    }
  }
}

// ---------------- stage 1: vertex->edge mean, quarter-wave, fp32 accum -----
__global__ __launch_bounds__(256) void edge_agg_q(
    const uint4* __restrict__ Xh4, const float* __restrict__ degE,
    const int* __restrict__ A_E, const int* __restrict__ C_E,
    const int* __restrict__ colE, uint4* __restrict__ Xe4, int E) {
  int ql = threadIdx.x & 15;
  int eid = blockIdx.x * 16 + (threadIdx.x >> 4);
  if (eid >= E) return;
  int s = A_E[eid], cnt = C_E[eid];
  float f0 = 0.f, f1 = 0.f, f2 = 0.f, f3 = 0.f, f4 = 0.f, f5 = 0.f, f6 = 0.f, f7 = 0.f;
  int idx = s, rem = cnt;
  while (rem > 0) {
    int r[16];
    #pragma unroll
    for (int t = 0; t < 16; ++t) r[t] = colE[idx + (t < rem ? t : 0)];
    #pragma unroll
    for (int t = 0; t < 16; ++t) {
      uint4 v = Xh4[(size_t)r[t] * 16 + ql];
      if (t < rem) {
        float2 p0 = __half22float2(u2h(v.x));
        float2 p1 = __half22float2(u2h(v.y));
        float2 p2 = __half22float2(u2h(v.z));
        float2 p3 = __half22float2(u2h(v.w));
        f0 += p0.x; f1 += p0.y; f2 += p1.x; f3 += p1.y;
        f4 += p2.x; f5 += p2.y; f6 += p3.x; f7 += p3.y;
      }
    }
    idx += 16;
    rem -= 16;
  }
  float scale = degE[eid] / fmaxf((float)cnt, 1.0f);
  uint4 o;
  o.x = pack_h2(f0 * scale, f1 * scale);
  o.y = pack_h2(f2 * scale, f3 * scale);
  o.z = pack_h2(f4 * scale, f5 * scale);
  o.w = pack_h2(f6 * scale, f7 * scale);
  Xe4[(size_t)eid * 16 + ql] = o;
}

// ---- fused stage 2+3 v3: 1024 thr; ONE vertex per quarter-wave (no outer
// loop -> no serial chains); barrier; 16 waves x 2 output tiles of MFMA.
__global__ __launch_bounds__(1024) void vertex_fused(
    const uint4* __restrict__ Xe4, const float* __restrict__ X0,
    const uint4* X0h, int useh,
    const float* __restrict__ degV, const float* __restrict__ ln_w,
    const float* __restrict__ ln_b, const float* __restrict__ alpha_p,
    const int* __restrict__ A_V, const int* __restrict__ C_V,
    const int* __restrict__ colV, const ushort* __restrict__ Wbf,
    float* __restrict__ out, int N) {
  __shared__ __align__(16) ushort XiT[64 * 136];   // 17 KB, padded rows
  int ql = threadIdx.x & 15;
  int grp = threadIdx.x >> 4;   // 0..63: one vertex per quarter-wave
  int n0 = blockIdx.x * 64;
  int n = n0 + grp;

  // ---- phase A: exactly the green vertex_ln_q body (single vertex) ----
  uint4 o = make_uint4(0u, 0u, 0u, 0u);
  if (n < N) {
    const f32x4* lw4 = (const f32x4*)ln_w;
    const f32x4* lb4 = (const f32x4*)ln_b;
    f32x4 lwa = lw4[ql * 2], lwb = lw4[ql * 2 + 1];
    f32x4 lba = lb4[ql * 2], lbb = lb4[ql * 2 + 1];
    float alpha = *alpha_p;
    int s = A_V[n], cnt = C_V[n];
    float f0 = 0.f, f1 = 0.f, f2 = 0.f, f3 = 0.f, f4 = 0.f, f5 = 0.f, f6 = 0.f, f7 = 0.f;
    int idx = s, rem = cnt;
    while (rem > 0) {
      int rr[8];
      #pragma unroll
      for (int t = 0; t < 8; ++t) rr[t] = colV[idx + (t < rem ? t : 0)];
      #pragma unroll
      for (int t = 0; t < 8; ++t) {
        uint4 v = Xe4[(size_t)rr[t] * 16 + ql];
        if (t < rem) {
          float2 p0 = __half22float2(u2h(v.x));
          float2 p1 = __half22float2(u2h(v.y));
          float2 p2 = __half22float2(u2h(v.z));
          float2 p3 = __half22float2(u2h(v.w));
          f0 += p0.x; f1 += p0.y; f2 += p1.x; f3 += p1.y;
          f4 += p2.x; f5 += p2.y; f6 += p3.x; f7 += p3.y;
        }
      }
      idx += 8;
      rem -= 8;
    }
    float sm = ((f0 + f1) + (f2 + f3)) + ((f4 + f5) + (f6 + f7));
    float qq = ((f0 * f0 + f1 * f1) + (f2 * f2 + f3 * f3)) +
               ((f4 * f4 + f5 * f5) + (f6 * f6 + f7 * f7));
    #pragma unroll
    for (int off = 1; off < 16; off <<= 1) {
      sm += __shfl_xor(sm, off);
      qq += __shfl_xor(qq, off);
    }
    float dv = degV[n];
    float csc = 2.f * dv;
    float mu = csc * sm * (1.f / 128.f);
    float var = csc * csc * qq * (1.f / 128.f) - mu * mu;
    float rstd = rsqrtf(var + 1e-5f);
    float x00[8];
    if (useh) {
      uint4 xh = X0h[(size_t)n * 16 + ql];
      float2 q0 = __half22float2(u2h(xh.x));
      float2 q1 = __half22float2(u2h(xh.y));
      float2 q2 = __half22float2(u2h(xh.z));
      float2 q3 = __half22float2(u2h(xh.w));
      x00[0] = q0.x; x00[1] = q0.y; x00[2] = q1.x; x00[3] = q1.y;
      x00[4] = q2.x; x00[5] = q2.y; x00[6] = q3.x; x00[7] = q3.y;
    } else {
      f32x4 x0a = ((const f32x4*)X0)[(size_t)n * 32 + ql * 2];
      f32x4 x0b = ((const f32x4*)X0)[(size_t)n * 32 + ql * 2 + 1];
      x00[0] = x0a[0]; x00[1] = x0a[1]; x00[2] = x0a[2]; x00[3] = x0a[3];
      x00[4] = x0b[0]; x00[5] = x0b[1]; x00[6] = x0b[2]; x00[7] = x0b[3];
    }
    float ff[8] = {f0, f1, f2, f3, f4, f5, f6, f7};
    float lww[8] = {lwa[0], lwa[1], lwa[2], lwa[3], lwb[0], lwb[1], lwb[2], lwb[3]};
    float lbs[8] = {lba[0], lba[1], lba[2], lba[3], lbb[0], lbb[1], lbb[2], lbb[3]};
    ushort ob[8];
    #pragma unroll
    for (int i = 0; i < 8; ++i) {
      float xhv = csc * ff[i];
      float xn = (xhv - mu) * rstd * lww[i] + lbs[i];
      float xi = (1.f - alpha) * xn + alpha * x00[i];
      ob[i] = f2bf(xi);
    }
    o.x = (unsigned)ob[0] | ((unsigned)ob[1] << 16);
    o.y = (unsigned)ob[2] | ((unsigned)ob[3] << 16);
    o.z = (unsigned)ob[4] | ((unsigned)ob[5] << 16);
    o.w = (unsigned)ob[6] | ((unsigned)ob[7] << 16);
  }
  *(uint4*)(&XiT[grp * 136 + ql * 8]) = o;   // padded store, 16B aligned
  __syncthreads();

  // ---- phase B: 16 waves x 2 tiles; verified gemm_out MFMA mapping ----
  int wv = threadIdx.x >> 6, lane = threadIdx.x & 63;
  const bf16x8* W8 = (const bf16x8*)Wbf;
  #pragma unroll
  for (int tt = 0; tt < 2; ++tt) {
    int tile = wv * 2 + tt;          // 0..31
    int rt = tile >> 3;              // row-tile 0..3
    int ct = tile & 7;               // col-tile 0..7
    f32x4 acc = {};
    #pragma unroll
    for (int ks = 0; ks < 4; ++ks) {
      int row = rt * 16 + (lane & 15);
      int slot = ks * 4 + (lane >> 4);
      bf16x8 a = *(const bf16x8*)(&XiT[row * 136 + slot * 8]);
      bf16x8 bb = W8[(ct * 16 + (lane & 15)) * 16 + slot];  // L1/L2-resident
      acc = __builtin_amdgcn_mfma_f32_16x16x32_bf16(a, bb, acc, 0, 0, 0);
    }
    #pragma unroll
    for (int i = 0; i < 4; ++i) {
      int row = n0 + rt * 16 + (lane >> 4) * 4 + i;
      int col = ct * 16 + (lane & 15);
      if (row < N) out[(size_t)row * 128 + col] = acc[i];
    }
  }
}

extern "C" void kernel_launch(void* const* d_in, const int* in_sizes, int n_in,
                              void* d_out, int out_size, void* d_ws, size_t ws_size,
                              hipStream_t stream) {
  const float* X     = (const float*)d_in[0];
  const float* X0    = (const float*)d_in[1];
  const float* degE  = (const float*)d_in[2];
  const float* degV  = (const float*)d_in[3];
  const float* W     = (const float*)d_in[4];
  const float* alpha = (const float*)d_in[5];
  const float* beta  = (const float*)d_in[6];
  const float* lnw   = (const float*)d_in[7];
  const float* lnb   = (const float*)d_in[8];
  const int* vertex  = (const int*)d_in[9];
  const int* edges   = (const int*)d_in[10];

  const int N = in_sizes[0] / D;
  const int E = in_sizes[2];
  const int M = in_sizes[9];

  const int BE = (E + 1023) >> 10;
  const int BV = (N + 1023) >> 10;

  char* p = (char*)d_ws;
  auto alloc = [&](size_t bytes) { char* r = p; p += (bytes + 255) & ~255ull; return r; };
  int* A_E  = (int*)alloc((size_t)E * 4);
  int* A_V  = (int*)alloc((size_t)N * 4);
  int* C_E  = (int*)alloc((size_t)E * 4);
  int* C_V  = (int*)alloc((size_t)N * 4);
  int* sums = (int*)alloc(1024);
  int* colE = (int*)alloc((size_t)M * 4);
  int* colV = (int*)alloc((size_t)M * 4);
  int* T_E  = (int*)alloc((size_t)NCH * E * 4);
  int* T_V  = (int*)alloc((size_t)NCH * N * 4);
  uint2* X_h  = (uint2*)alloc((size_t)N * D * 2);      // N x 128 fp16
  uint4* Xe4  = (uint4*)alloc((size_t)E * D * 2);      // E x 128 fp16
  ushort* Wbf = (ushort*)alloc(16384 * 2);

  // optional fp16 X0 (guarded: only if workspace has room beyond verified base)
  size_t used = (size_t)(p - (char*)d_ws);
  size_t x0h_bytes = ((size_t)N * D * 2 + 255) & ~255ull;
  int do_x0 = (used + x0h_bytes <= ws_size) ? 1 : 0;
  uint2* X0h = do_x0 ? (uint2*)alloc((size_t)N * D * 2) : nullptr;

  count_tab<<<NRR * NCH + CVT_BLOCKS, 512, 0, stream>>>(
      edges, vertex, T_E, T_V, E, N, M, X, X_h, X0, X0h, do_x0, N * D / 4);
  scan_fused<<<BE + BV, 1024, 0, stream>>>(T_E, C_E, A_E, E, T_V, C_V, A_V, N, sums, BE);
  scan_add2<<<BE + BV + 16, 1024, 0, stream>>>(A_E, E, A_V, N, sums, BE, BV, W, beta, Wbf);
  scatter_tab<<<NRR * NCH, 512, 0, stream>>>(edges, vertex, A_E, A_V, T_E, T_V,
                                             colE, colV, E, N, M);
  edge_agg_q<<<(E + 15) / 16, 256, 0, stream>>>((const uint4*)X_h, degE, A_E, C_E,
                                                colE, Xe4, E);
  vertex_fused<<<(N + 63) / 64, 1024, 0, stream>>>(
      Xe4, X0, (const uint4*)X0h, do_x0, degV, lnw, lnb, alpha,
      A_V, C_V, colV, Wbf, (float*)d_out, N);
}

// Round 17
// 137.422 us; speedup vs baseline: 1.2447x; 1.2447x over previous
//
#include <hip/hip_runtime.h>
#include <hip/hip_fp16.h>
#include <hip/hip_bf16.h>

#define D 128
#define NCH 16       // chunks (table dimension, count + scan + scatter)
#define NRE 4        // E-side histogram ranges
#define NRV 8        // V-side histogram ranges
#define E_BLKS (NRE * NCH)   // 64
#define V_BLKS (NRV * NCH)   // 128
#define H_SL 12544   // >= max(ceil(E/NRE)=6250, ceil(N/NRV)=12500)
#define SNR 16       // scatter ranges
#define CVT_BLOCKS 512
#define RE_SL 1600   // >= ceil(E/SNR)
#define RV_SL 6272   // >= ceil(N/SNR)

typedef __attribute__((ext_vector_type(8))) short bf16x8;
typedef __attribute__((ext_vector_type(4))) float f32x4;

__device__ __forceinline__ __half2 u2h(unsigned u) { return __builtin_bit_cast(__half2, u); }
__device__ __forceinline__ unsigned pack_h2(float a, float b) {
  __half2 h = __float22half2_rn(make_float2(a, b));
  return __builtin_bit_cast(unsigned, h);
}
__device__ __forceinline__ ushort f2bf(float x) {
  __hip_bfloat16 b = __float2bfloat16(x);
  return __builtin_bit_cast(ushort, b);
}

// ------- count: role-split histograms (block reads ONE array) + cvt --------
__global__ __launch_bounds__(512) void count_tab(
    const int* __restrict__ edges, const int* __restrict__ vertex,
    int* __restrict__ T_E, int* __restrict__ T_V, int E, int N, int M,
    const float* __restrict__ X, uint2* __restrict__ Xh,
    const float* __restrict__ X0, uint2* X0h, int do_x0, int xn4) {
  __shared__ int h[H_SL];
  int b = blockIdx.x;
  if (b >= E_BLKS + V_BLKS) {
    const f32x4* X4 = (const f32x4*)X;
    const f32x4* X04 = (const f32x4*)X0;
    int stride = (gridDim.x - E_BLKS - V_BLKS) * 512;
    int lim = do_x0 ? (2 * xn4) : xn4;
    for (int i = (b - E_BLKS - V_BLKS) * 512 + threadIdx.x; i < lim; i += stride) {
      int j = (i < xn4) ? i : (i - xn4);
      f32x4 v = (i < xn4) ? X4[j] : X04[j];
      uint2 o = make_uint2(pack_h2(v[0], v[1]), pack_h2(v[2], v[3]));
      if (i < xn4) Xh[j] = o; else X0h[j] = o;
    }
    return;
  }
  const int* keys; int* T; int lo, hi, c, total;
  if (b < E_BLKS) {
    int r = b & (NRE - 1); c = b >> 2;
    int R = (E + NRE - 1) / NRE;
    lo = r * R; hi = min(lo + R, E); keys = edges; T = T_E; total = E;
  } else {
    int bb = b - E_BLKS;
    int r = bb & (NRV - 1); c = bb >> 3;
    int R = (N + NRV - 1) / NRV;
    lo = r * R; hi = min(lo + R, N); keys = vertex; T = T_V; total = N;
  }
  int len = hi - lo;
  for (int i = threadIdx.x; i < len; i += 512) h[i] = 0;
  __syncthreads();
  const int4* K4 = (const int4*)keys;
  int m4 = M >> 2;
  int per = (m4 + NCH - 1) / NCH;
  int i0 = c * per, i1 = min(i0 + per, m4);

#define PROC1(k)                                                       \
  {                                                                    \
    if ((k).x >= lo && (k).x < hi) atomicAdd(&h[(k).x - lo], 1);       \
    if ((k).y >= lo && (k).y < hi) atomicAdd(&h[(k).y - lo], 1);       \
    if ((k).z >= lo && (k).z < hi) atomicAdd(&h[(k).z - lo], 1);       \
    if ((k).w >= lo && (k).w < hi) atomicAdd(&h[(k).w - lo], 1);       \
  }

  int i = i0 + threadIdx.x;
  for (; i + 1536 < i1; i += 2048) {  // 4 int4 loads in flight
    int4 k0 = K4[i], k1 = K4[i + 512], k2 = K4[i + 1024], k3 = K4[i + 1536];
    PROC1(k0); PROC1(k1); PROC1(k2); PROC1(k3);
  }
  for (; i < i1; i += 512) {
    int4 k = K4[i];
    PROC1(k);
  }
  if (c == NCH - 1) {  // scalar tail if M % 4 != 0
    for (int m = (m4 << 2) + threadIdx.x; m < M; m += 512) {
      int k = keys[m];
      if (k >= lo && k < hi) atomicAdd(&h[k - lo], 1);
    }
  }
  __syncthreads();
  for (int i2 = threadIdx.x; i2 < len; i2 += 512) T[(size_t)c * total + lo + i2] = h[i2];
}

// ---------------- block exclusive scan helper ------------------------------
__device__ __forceinline__ int block_exscan(int x, int tid, int* wsum) {
  int lane = tid & 63, w = tid >> 6;
  int v = x;
  #pragma unroll
  for (int off = 1; off < 64; off <<= 1) {
    int t = __shfl_up(v, off);
    if (lane >= off) v += t;
  }
  if (lane == 63) wsum[w] = v;
  __syncthreads();
  if (w == 0 && lane < 16) {
    int s = wsum[lane];
    #pragma unroll
    for (int off = 1; off < 16; off <<= 1) {
      int t = __shfl_up(s, off);
      if (lane >= off) s += t;
    }
    wsum[lane] = s;
  }
  __syncthreads();
  int woff = (w == 0) ? 0 : wsum[w - 1];
  return woff + v - x;
}

// ------- fused: per-id chunk prefix (T in place) + C + local scan ----------
__global__ __launch_bounds__(1024) void scan_fused(
    int* __restrict__ T_E, int* __restrict__ C_E, int* __restrict__ A_E, int E,
    int* __restrict__ T_V, int* __restrict__ C_V, int* __restrict__ A_V, int N,
    int* __restrict__ sums, int BE) {
  __shared__ int wsum[16];
  int b = blockIdx.x;
  bool isE = b < BE;
  int* T = isE ? T_E : T_V;
  int* C = isE ? C_E : C_V;
  int* A = isE ? A_E : A_V;
  int len = isE ? E : N;
  int base = (isE ? b : (b - BE)) << 10;
  int id = base + threadIdx.x;
  int run = 0;
  if (id < len) {
    #pragma unroll
    for (int c = 0; c < NCH; ++c) {
      int t = T[(size_t)c * len + id];
      T[(size_t)c * len + id] = run;
      run += t;
    }
    C[id] = run;
  }
  int ex = block_exscan(run, threadIdx.x, wsum);
  if (id < len) A[id] = ex;
  if (threadIdx.x == 0) sums[b] = wsum[15];
}

// ------- add block offsets (redundant local scan of sums) + wprep ----------
__global__ __launch_bounds__(1024) void scan_add2(
    int* __restrict__ A_E, int E, int* __restrict__ A_V, int N,
    const int* __restrict__ sums, int BE, int BV,
    const float* __restrict__ W, const float* __restrict__ beta_p,
    ushort* __restrict__ Wbf) {
  int nb = BE + BV;
  if ((int)blockIdx.x >= nb) {  // wprep blocks
    int idx = (blockIdx.x - nb) * 1024 + threadIdx.x;
    if (idx < D * D) {
      int j = idx >> 7, k = idx & 127;
      float beta = *beta_p;
      float v = beta * W[idx] + ((j == k) ? (1.f - beta) : 0.f);
      Wbf[idx] = f2bf(v);
    }
    return;
  }
  __shared__ int wsum[16];
  __shared__ int pb, pbe;
  int x = ((int)threadIdx.x < nb) ? sums[threadIdx.x] : 0;
  int ex = block_exscan(x, threadIdx.x, wsum);
  if (threadIdx.x == blockIdx.x) pb = ex;
  if ((int)threadIdx.x == BE) pbe = ex;
  __syncthreads();
  bool isE = (int)blockIdx.x < BE;
  int off = isE ? pb : (pb - pbe);
  int* A = isE ? A_E : A_V;
  int len = isE ? E : N;
  int base = (isE ? blockIdx.x : (blockIdx.x - BE)) << 10;
  int i = base + threadIdx.x;
  if (i < len) A[i] += off;
}

// ------- scatter: deterministic slots, LDS-only ranking; x2 unroll ---------
__global__ __launch_bounds__(512) void scatter_tab(
    const int* __restrict__ edges, const int* __restrict__ vertex,
    const int* __restrict__ A_E, const int* __restrict__ A_V,
    const int* __restrict__ T_E, const int* __restrict__ T_V,
    int* __restrict__ colE, int* __restrict__ colV, int E, int N, int M) {
  __shared__ int offE[RE_SL];
  __shared__ int curE[RE_SL];
  __shared__ int offV[RV_SL];
  __shared__ int curV[RV_SL];
  int b = blockIdx.x;
  int r = b & (SNR - 1), c = b >> 4;
  int RE = (E + SNR - 1) / SNR, RV = (N + SNR - 1) / SNR;
  int eLo = r * RE, eHi = min(eLo + RE, E);
  int vLo = r * RV, vHi = min(vLo + RV, N);
  int eLen = eHi - eLo, vLen = vHi - vLo;
  for (int i = threadIdx.x; i < eLen; i += 512) {
    offE[i] = A_E[eLo + i] + T_E[(size_t)c * E + eLo + i];
    curE[i] = 0;
  }
  for (int i = threadIdx.x; i < vLen; i += 512) {
    offV[i] = A_V[vLo + i] + T_V[(size_t)c * N + vLo + i];
    curV[i] = 0;
  }
  __syncthreads();
  const int4* E4 = (const int4*)edges;
  const int4* V4 = (const int4*)vertex;
  int m4 = M >> 2;
  int per = (m4 + NCH - 1) / NCH;
  int i0 = c * per, i1 = min(i0 + per, m4);

#define PROC_SCAT(ek, vk)                                                   \
  {                                                                         \
    int es_[4] = {(ek).x, (ek).y, (ek).z, (ek).w};                          \
    int vs_[4] = {(vk).x, (vk).y, (vk).z, (vk).w};                          \
    _Pragma("unroll")                                                       \
    for (int t = 0; t < 4; ++t) {                                           \
      if (es_[t] >= eLo && es_[t] < eHi) {                                  \
        int p2 = atomicAdd(&curE[es_[t] - eLo], 1);                         \
        colE[offE[es_[t] - eLo] + p2] = vs_[t];                             \
      }                                                                     \
      if (vs_[t] >= vLo && vs_[t] < vHi) {                                  \
        int p2 = atomicAdd(&curV[vs_[t] - vLo], 1);                         \
        colV[offV[vs_[t] - vLo] + p2] = es_[t];                             \
      }                                                                     \
    }                                                                       \
  }

  int i = i0 + threadIdx.x;
  for (; i + 512 < i1; i += 1024) {
    int4 ea = E4[i], eb = E4[i + 512];
    int4 va = V4[i], vb = V4[i + 512];
    PROC_SCAT(ea, va);
    PROC_SCAT(eb, vb);
  }
  for (; i < i1; i += 512) {
    int4 ek = E4[i];
    int4 vk = V4[i];
    PROC_SCAT(ek, vk);
  }
  if (c == NCH - 1) {
    for (int m = (m4 << 2) + threadIdx.x; m < M; m += 512) {
      int e = edges[m], v = vertex[m];
      if (e >= eLo && e < eHi) {
        int p = atomicAdd(&curE[e - eLo], 1);
        colE[offE[e - eLo] + p] = v;
      }
      if (v >= vLo && v < vHi) {
        int p = atomicAdd(&curV[v - vLo], 1);
        colV[offV[v - vLo] + p] = e;
      }
    }
  }
}

// ---------------- stage 1: vertex->edge mean, quarter-wave, fp32 accum -----
__global__ __launch_bounds__(256) void edge_agg_q(
    const uint4* __restrict__ Xh4, const float* __restrict__ degE,
    const int* __restrict__ A_E, const int* __restrict__ C_E,
    const int* __restrict__ colE, uint4* __restrict__ Xe4, int E) {
  int ql = threadIdx.x & 15;
  int eid = blockIdx.x * 16 + (threadIdx.x >> 4);
  if (eid >= E) return;
  int s = A_E[eid], cnt = C_E[eid];
  float f0 = 0.f, f1 = 0.f, f2 = 0.f, f3 = 0.f, f4 = 0.f, f5 = 0.f, f6 = 0.f, f7 = 0.f;
  int idx = s, rem = cnt;
  while (rem > 0) {
    int r[16];
    #pragma unroll
    for (int t = 0; t < 16; ++t) r[t] = colE[idx + (t < rem ? t : 0)];
    #pragma unroll
    for (int t = 0; t < 16; ++t) {
      uint4 v = Xh4[(size_t)r[t] * 16 + ql];
      if (t < rem) {
        float2 p0 = __half22float2(u2h(v.x));
        float2 p1 = __half22float2(u2h(v.y));
        float2 p2 = __half22float2(u2h(v.z));
        float2 p3 = __half22float2(u2h(v.w));
        f0 += p0.x; f1 += p0.y; f2 += p1.x; f3 += p1.y;
        f4 += p2.x; f5 += p2.y; f6 += p3.x; f7 += p3.y;
      }
    }
    idx += 16;
    rem -= 16;
  }
  float scale = degE[eid] / fmaxf((float)cnt, 1.0f);
  uint4 o;
  o.x = pack_h2(f0 * scale, f1 * scale);
  o.y = pack_h2(f2 * scale, f3 * scale);
  o.z = pack_h2(f4 * scale, f5 * scale);
  o.w = pack_h2(f6 * scale, f7 * scale);
  Xe4[(size_t)eid * 16 + ql] = o;
}

// ---------------- stage 2: edge->vertex sum + LN + combine, quarter-wave ---
__global__ __launch_bounds__(256) void vertex_ln_q(
    const uint4* __restrict__ Xe4, const float* __restrict__ X0,
    const uint4* X0h, int useh,
    const float* __restrict__ degV, const float* __restrict__ ln_w,
    const float* __restrict__ ln_b, const float* __restrict__ alpha_p,
    const int* __restrict__ A_V, const int* __restrict__ C_V,
    const int* __restrict__ colV, uint4* __restrict__ Xi4, int N) {
  int ql = threadIdx.x & 15;
  int n = blockIdx.x * 16 + (threadIdx.x >> 4);
  if (n >= N) return;
  int s = A_V[n], cnt = C_V[n];
  float f0 = 0.f, f1 = 0.f, f2 = 0.f, f3 = 0.f, f4 = 0.f, f5 = 0.f, f6 = 0.f, f7 = 0.f;
  int idx = s, rem = cnt;
  while (rem > 0) {
    int r[8];
    #pragma unroll
    for (int t = 0; t < 8; ++t) r[t] = colV[idx + (t < rem ? t : 0)];
    #pragma unroll
    for (int t = 0; t < 8; ++t) {
      uint4 v = Xe4[(size_t)r[t] * 16 + ql];
      if (t < rem) {
        float2 p0 = __half22float2(u2h(v.x));
        float2 p1 = __half22float2(u2h(v.y));
        float2 p2 = __half22float2(u2h(v.z));
        float2 p3 = __half22float2(u2h(v.w));
        f0 += p0.x; f1 += p0.y; f2 += p1.x; f3 += p1.y;
        f4 += p2.x; f5 += p2.y; f6 += p3.x; f7 += p3.y;
      }
    }
    idx += 8;
    rem -= 8;
  }
  float sm = ((f0 + f1) + (f2 + f3)) + ((f4 + f5) + (f6 + f7));
  float qq = ((f0 * f0 + f1 * f1) + (f2 * f2 + f3 * f3)) +
             ((f4 * f4 + f5 * f5) + (f6 * f6 + f7 * f7));
  #pragma unroll
  for (int off = 1; off < 16; off <<= 1) {
    sm += __shfl_xor(sm, off);
    qq += __shfl_xor(qq, off);
  }
  float dv = degV[n];
  float csc = 2.f * dv;
  float mu = csc * sm * (1.f / 128.f);
  float var = csc * csc * qq * (1.f / 128.f) - mu * mu;
  float rstd = rsqrtf(var + 1e-5f);
  float x00[8];
  if (useh) {
    uint4 xh = X0h[(size_t)n * 16 + ql];
    float2 q0 = __half22float2(u2h(xh.x));
    float2 q1 = __half22float2(u2h(xh.y));
    float2 q2 = __half22float2(u2h(xh.z));
    float2 q3 = __half22float2(u2h(xh.w));
    x00[0] = q0.x; x00[1] = q0.y; x00[2] = q1.x; x00[3] = q1.y;
    x00[4] = q2.x; x00[5] = q2.y; x00[6] = q3.x; x00[7] = q3.y;
  } else {
    f32x4 x0a = ((const f32x4*)X0)[(size_t)n * 32 + ql * 2];
    f32x4 x0b = ((const f32x4*)X0)[(size_t)n * 32 + ql * 2 + 1];
    x00[0] = x0a[0]; x00[1] = x0a[1]; x00[2] = x0a[2]; x00[3] = x0a[3];
    x00[4] = x0b[0]; x00[5] = x0b[1]; x00[6] = x0b[2]; x00[7] = x0b[3];
  }
  const f32x4* lw4 = (const f32x4*)ln_w;
  const f32x4* lb4 = (const f32x4*)ln_b;
  f32x4 lwa = lw4[ql * 2], lwb = lw4[ql * 2 + 1];
  f32x4 lba = lb4[ql * 2], lbb = lb4[ql * 2 + 1];
  float alpha = *alpha_p;
  float ff[8] = {f0, f1, f2, f3, f4, f5, f6, f7};
  float lww[8] = {lwa[0], lwa[1], lwa[2], lwa[3], lwb[0], lwb[1], lwb[2], lwb[3]};
  float lbs[8] = {lba[0], lba[1], lba[2], lba[3], lbb[0], lbb[1], lbb[2], lbb[3]};
  ushort ob[8];
  #pragma unroll
  for (int i = 0; i < 8; ++i) {
    float xh = csc * ff[i];
    float xn = (xh - mu) * rstd * lww[i] + lbs[i];
    float xi = (1.f - alpha) * xn + alpha * x00[i];
    ob[i] = f2bf(xi);
  }
  uint4 o;
  o.x = (unsigned)ob[0] | ((unsigned)ob[1] << 16);
  o.y = (unsigned)ob[2] | ((unsigned)ob[3] << 16);
  o.z = (unsigned)ob[4] | ((unsigned)ob[5] << 16);
  o.w = (unsigned)ob[6] | ((unsigned)ob[7] << 16);
  Xi4[(size_t)n * 16 + ql] = o;
}

// ---------------- stage 3: out = Xi @ Weff via MFMA bf16 ------------------
__global__ __launch_bounds__(256) void gemm_out(
    const ushort* __restrict__ Xi_bf, const ushort* __restrict__ Wbf,
    float* __restrict__ out, int N) {
  __shared__ __align__(16) ushort Wl[128 * 128];
  for (int t = threadIdx.x; t < 2048; t += 256) {
    int j = t >> 4, chunk = t & 15;
    bf16x8 v = ((const bf16x8*)Wbf)[t];
    ((bf16x8*)Wl)[j * 16 + (chunk ^ (j & 7))] = v;
  }
  __syncthreads();
  int wv = threadIdx.x >> 6, lane = threadIdx.x & 63;
  int row0 = blockIdx.x * 128 + wv * 32;
  f32x4 acc[2][8] = {};
  #pragma unroll
  for (int ks = 0; ks < 4; ++ks) {
    bf16x8 a[2];
    #pragma unroll
    for (int rt = 0; rt < 2; ++rt) {
      int row = row0 + rt * 16 + (lane & 15);
      row = row < N ? row : N - 1;
      a[rt] = *(const bf16x8*)(Xi_bf + (size_t)row * 128 + ks * 32 + (lane >> 4) * 8);
    }
    int chunk = ks * 4 + (lane >> 4);
    #pragma unroll
    for (int c = 0; c < 8; ++c) {
      int col = c * 16 + (lane & 15);
      bf16x8 bb = ((const bf16x8*)Wl)[col * 16 + (chunk ^ (col & 7))];
      acc[0][c] = __builtin_amdgcn_mfma_f32_16x16x32_bf16(a[0], bb, acc[0][c], 0, 0, 0);
      acc[1][c] = __builtin_amdgcn_mfma_f32_16x16x32_bf16(a[1], bb, acc[1][c], 0, 0, 0);
    }
  }
  #pragma unroll
  for (int rt = 0; rt < 2; ++rt) {
    #pragma unroll
    for (int c = 0; c < 8; ++c) {
      #pragma unroll
      for (int i = 0; i < 4; ++i) {
        int row = row0 + rt * 16 + (lane >> 4) * 4 + i;
        int col = c * 16 + (lane & 15);
        if (row < N) out[(size_t)row * 128 + col] = acc[rt][c][i];
      }
    }
  }
}

extern "C" void kernel_launch(void* const* d_in, const int* in_sizes, int n_in,
                              void* d_out, int out_size, void* d_ws, size_t ws_size,
                              hipStream_t stream) {
  const float* X     = (const float*)d_in[0];
  const float* X0    = (const float*)d_in[1];
  const float* degE  = (const float*)d_in[2];
  const float* degV  = (const float*)d_in[3];
  const float* W     = (const float*)d_in[4];
  const float* alpha = (const float*)d_in[5];
  const float* beta  = (const float*)d_in[6];
  const float* lnw   = (const float*)d_in[7];
  const float* lnb   = (const float*)d_in[8];
  const int* vertex  = (const int*)d_in[9];
  const int* edges   = (const int*)d_in[10];

  const int N = in_sizes[0] / D;
  const int E = in_sizes[2];
  const int M = in_sizes[9];

  const int BE = (E + 1023) >> 10;
  const int BV = (N + 1023) >> 10;

  char* p = (char*)d_ws;
  auto alloc = [&](size_t bytes) { char* r = p; p += (bytes + 255) & ~255ull; return r; };
  int* A_E  = (int*)alloc((size_t)E * 4);
  int* A_V  = (int*)alloc((size_t)N * 4);
  int* C_E  = (int*)alloc((size_t)E * 4);
  int* C_V  = (int*)alloc((size_t)N * 4);
  int* sums = (int*)alloc(1024);
  int* colE = (int*)alloc((size_t)M * 4);
  int* colV = (int*)alloc((size_t)M * 4);
  int* T_E  = (int*)alloc((size_t)NCH * E * 4);
  int* T_V  = (int*)alloc((size_t)NCH * N * 4);
  uint2* X_h  = (uint2*)alloc((size_t)N * D * 2);      // N x 128 fp16
  uint4* Xe4  = (uint4*)alloc((size_t)E * D * 2);      // E x 128 fp16
  ushort* Wbf = (ushort*)alloc(16384 * 2);
  uint4* Xi4  = (uint4*)X_h;  // X_h dead after edge_agg_q; alias for Xi (bf16)

  // optional fp16 X0 (guarded: only if workspace has room beyond verified base)
  size_t used = (size_t)(p - (char*)d_ws);
  size_t x0h_bytes = ((size_t)N * D * 2 + 255) & ~255ull;
  int do_x0 = (used + x0h_bytes <= ws_size) ? 1 : 0;
  uint2* X0h = do_x0 ? (uint2*)alloc((size_t)N * D * 2) : nullptr;

  count_tab<<<E_BLKS + V_BLKS + CVT_BLOCKS, 512, 0, stream>>>(
      edges, vertex, T_E, T_V, E, N, M, X, X_h, X0, X0h, do_x0, N * D / 4);
  scan_fused<<<BE + BV, 1024, 0, stream>>>(T_E, C_E, A_E, E, T_V, C_V, A_V, N, sums, BE);
  scan_add2<<<BE + BV + 16, 1024, 0, stream>>>(A_E, E, A_V, N, sums, BE, BV, W, beta, Wbf);
  scatter_tab<<<SNR * NCH, 512, 0, stream>>>(edges, vertex, A_E, A_V, T_E, T_V,
                                             colE, colV, E, N, M);
  edge_agg_q<<<(E + 15) / 16, 256, 0, stream>>>((const uint4*)X_h, degE, A_E, C_E,
                                                colE, Xe4, E);
  vertex_ln_q<<<(N + 15) / 16, 256, 0, stream>>>(Xe4, X0, (const uint4*)X0h, do_x0,
                                                 degV, lnw, lnb, alpha,
                                                 A_V, C_V, colV, Xi4, N);
  gemm_out<<<(N + 127) / 128, 256, 0, stream>>>((const ushort*)Xi4, Wbf, (float*)d_out, N);
}